// Round 13
// baseline (831.979 us; speedup 1.0000x reference)
//
#include <hip/hip_runtime.h>
#include <hip/hip_bf16.h>

// Fused MHA+RoPE pipeline for MI355X (gfx950), bf16 MFMA throughout.
// B=4, S=2048, E=2048, H=16, D=128, M=B*S=8192.

typedef __bf16 bf16;
typedef __bf16 bf16x8 __attribute__((ext_vector_type(8)));
typedef __bf16 bf16x4 __attribute__((ext_vector_type(4)));
typedef __bf16 bf16x2 __attribute__((ext_vector_type(2)));
typedef float  f32x4  __attribute__((ext_vector_type(4)));
typedef float  f32x16 __attribute__((ext_vector_type(16)));

constexpr int Bc = 4, Sc = 2048, Ec = 2048, Hc = 16, Dc = 128;
constexpr int Mc = Bc * Sc; // 8192

__device__ __forceinline__ void async16(const void* g, void* l) {
  __builtin_amdgcn_global_load_lds(
      (const __attribute__((address_space(1))) void*)g,
      (__attribute__((address_space(3))) void*)l, 16, 0, 0);
}

__device__ __forceinline__ unsigned int pkbf(float a, float b) {
  union { bf16x2 v; unsigned int u; } c;
  c.v[0] = (bf16)a; c.v[1] = (bf16)b;
  return c.u;
}

// ---------------- fp32 -> bf16 convert (multi-job, vectorized) ----------------
__global__ void cvt_multi(const float* s0, const float* s1, const float* s2, const float* s3,
                          bf16* d0, bf16* d1, bf16* d2, bf16* d3, int n8) {
  const float* src; bf16* dst;
  switch (blockIdx.y) {
    case 0:  src = s0; dst = d0; break;
    case 1:  src = s1; dst = d1; break;
    case 2:  src = s2; dst = d2; break;
    default: src = s3; dst = d3; break;
  }
  int i = blockIdx.x * blockDim.x + threadIdx.x;
  const int stride = gridDim.x * blockDim.x;
  for (; i < n8; i += stride) {
    const float4 a = *((const float4*)src + (size_t)i * 2);
    const float4 b = *((const float4*)src + (size_t)i * 2 + 1);
    bf16x8 o;
    o[0] = (bf16)a.x; o[1] = (bf16)a.y; o[2] = (bf16)a.z; o[3] = (bf16)a.w;
    o[4] = (bf16)b.x; o[5] = (bf16)b.y; o[6] = (bf16)b.z; o[7] = (bf16)b.w;
    *(bf16x8*)(dst + (size_t)i * 8) = o;
  }
}

// ---------------- GEMM: C[m][n] = sum_k A[m][k]*B[n][k] + bias[n] ----------------
// 8-PHASE (r12, proven: ~57us/dispatch): 256x256 tile, BK=64, 8 waves (2Mx4N),
// double-buffered 128KB LDS, XOR-swizzled granules g^(row&7) (pre-swizzled global
// source, linear LDS dest). 4 phases per K-tile, one C-quadrant x K=64 per phase.
// Counted vmcnt per the r12 wait algebra; never 0 in steady state.
// OUT: 0 = f32 linear, 1 = bf16 linear, 2 = bf16 transposed into Vt[bh][d][s].
template <int OUT>
__global__ __launch_bounds__(512, 2) void gemm8(
    const bf16* __restrict__ A, const bf16* __restrict__ Bm,
    const float* __restrict__ bias, void* __restrict__ Cout, int Mblocks)
{
  __shared__ __align__(16) bf16 lds[2 * 32768]; // 128KB
  const int tid = threadIdx.x;
  const int w = tid >> 6, lane = tid & 63;
  const int l15 = lane & 15, l16 = lane >> 4;
  const int wm = w >> 2, wn = w & 3;
  const int id = blockIdx.x;
  const int nwg = Mblocks * 8, cpx = nwg >> 3;
  const int swz = (id & 7) * cpx + (id >> 3);
  const int by = swz >> 3, bx = swz & 7;
  const long m0 = (long)by * 256, n0 = (long)bx * 256;
  constexpr int NT = 32; // K/64

  auto stA = [&](int buf, long kt, int p, int j) {
    int ca = p + 2 * j;
    int row = ca * 64 + (tid >> 3);
    async16(A + (m0 + row) * 2048 + kt + (((tid & 7) ^ (row & 7)) << 3),
            &lds[buf * 32768 + ca * 4096 + tid * 8]);
  };
  auto stB = [&](int buf, long kt, int p, int j) {
    int cb = p + 4 * j + 2 * (tid >> 8);
    int row = cb * 32 + ((tid & 255) >> 3);
    async16(Bm + (n0 + row) * 2048 + kt + (((tid & 7) ^ (row & 7)) << 3),
            &lds[buf * 32768 + 16384 + (p + 4 * j) * 2048 + (tid >> 8) * 4096 + (tid & 255) * 8]);
  };

  f32x4 acc[8][4];
#pragma unroll
  for (int a = 0; a < 8; ++a)
#pragma unroll
    for (int b = 0; b < 4; ++b) acc[a][b] = f32x4{0.f, 0.f, 0.f, 0.f};

  stA(0, 0, 0, 0); stA(0, 0, 0, 1);
  stB(0, 0, 0, 0); stB(0, 0, 0, 1);
  stB(0, 0, 1, 0); stB(0, 0, 1, 1);
  stA(0, 0, 1, 0); stA(0, 0, 1, 1);
  asm volatile("s_waitcnt vmcnt(4)" ::: "memory"); // A0(0),B0(0) resident
  __builtin_amdgcn_s_barrier();

  for (int t = 0; t < NT; ++t) {
    const int buf = t & 1, nbuf = buf ^ 1;
    const int base = buf * 32768;
    const long ktn = (long)(t + 1) * 64;
    const bool pf = (t < NT - 1);
    bf16x8 fa[4][2], fb0[2][2], fb1[2][2];

    // ---- phase 0: quadrant (mh0, nh0) ----
#pragma unroll
    for (int mf = 0; mf < 4; ++mf)
#pragma unroll
      for (int ks = 0; ks < 2; ++ks) {
        int row = wm * 128 + mf * 16 + l15;
        fa[mf][ks] = *(const bf16x8*)&lds[base + row * 64 + (((ks * 4 + l16) ^ (row & 7)) << 3)];
      }
#pragma unroll
    for (int nf = 0; nf < 2; ++nf)
#pragma unroll
      for (int ks = 0; ks < 2; ++ks) {
        int row = wn * 64 + nf * 16 + l15;
        fb0[nf][ks] = *(const bf16x8*)&lds[base + 16384 + row * 64 + (((ks * 4 + l16) ^ (row & 7)) << 3)];
      }
    asm volatile("s_waitcnt vmcnt(2)" ::: "memory"); // B1(t) in LDS for ph1
    asm volatile("" ::: "memory");
    __builtin_amdgcn_s_barrier();
    __builtin_amdgcn_s_setprio(1);
#pragma unroll
    for (int mf = 0; mf < 4; ++mf)
#pragma unroll
      for (int nf = 0; nf < 2; ++nf)
#pragma unroll
        for (int ks = 0; ks < 2; ++ks)
          acc[mf][nf] = __builtin_amdgcn_mfma_f32_16x16x32_bf16(fa[mf][ks], fb0[nf][ks], acc[mf][nf], 0, 0, 0);
    __builtin_amdgcn_s_setprio(0);

    // ---- phase 1: quadrant (mh0, nh1); stage A0(t+1), B0(t+1) ----
#pragma unroll
    for (int nf = 0; nf < 2; ++nf)
#pragma unroll
      for (int ks = 0; ks < 2; ++ks) {
        int row = wn * 64 + 32 + nf * 16 + l15;
        fb1[nf][ks] = *(const bf16x8*)&lds[base + 16384 + row * 64 + (((ks * 4 + l16) ^ (row & 7)) << 3)];
      }
    if (pf) { stA(nbuf, ktn, 0, 0); stA(nbuf, ktn, 0, 1); stB(nbuf, ktn, 0, 0); stB(nbuf, ktn, 0, 1); }
    if (pf) { asm volatile("s_waitcnt vmcnt(4)" ::: "memory"); } // A1(t) in LDS for ph2
    else    { asm volatile("s_waitcnt vmcnt(0)" ::: "memory"); }
    asm volatile("" ::: "memory");
    __builtin_amdgcn_s_barrier();
    __builtin_amdgcn_s_setprio(1);
#pragma unroll
    for (int mf = 0; mf < 4; ++mf)
#pragma unroll
      for (int nf = 0; nf < 2; ++nf)
#pragma unroll
        for (int ks = 0; ks < 2; ++ks)
          acc[mf][2 + nf] = __builtin_amdgcn_mfma_f32_16x16x32_bf16(fa[mf][ks], fb1[nf][ks], acc[mf][2 + nf], 0, 0, 0);
    __builtin_amdgcn_s_setprio(0);

    // ---- phase 2: quadrant (mh1, nh0); stage B1(t+1) ----
#pragma unroll
    for (int mf = 0; mf < 4; ++mf)
#pragma unroll
      for (int ks = 0; ks < 2; ++ks) {
        int row = wm * 128 + 64 + mf * 16 + l15;
        fa[mf][ks] = *(const bf16x8*)&lds[base + row * 64 + (((ks * 4 + l16) ^ (row & 7)) << 3)];
      }
    if (pf) { stB(nbuf, ktn, 1, 0); stB(nbuf, ktn, 1, 1); }
    asm volatile("" ::: "memory");
    __builtin_amdgcn_s_barrier();
    __builtin_amdgcn_s_setprio(1);
#pragma unroll
    for (int mf = 0; mf < 4; ++mf)
#pragma unroll
      for (int nf = 0; nf < 2; ++nf)
#pragma unroll
        for (int ks = 0; ks < 2; ++ks)
          acc[4 + mf][nf] = __builtin_amdgcn_mfma_f32_16x16x32_bf16(fa[mf][ks], fb0[nf][ks], acc[4 + mf][nf], 0, 0, 0);
    __builtin_amdgcn_s_setprio(0);

    // ---- phase 3: quadrant (mh1, nh1); stage A1(t+1) ----
    if (pf) {
      stA(nbuf, ktn, 1, 0); stA(nbuf, ktn, 1, 1);
      asm volatile("s_waitcnt vmcnt(4)" ::: "memory"); // A0(t+1),B0(t+1) for next ph0
    }
    asm volatile("" ::: "memory");
    __builtin_amdgcn_s_barrier();
    __builtin_amdgcn_s_setprio(1);
#pragma unroll
    for (int mf = 0; mf < 4; ++mf)
#pragma unroll
      for (int nf = 0; nf < 2; ++nf)
#pragma unroll
        for (int ks = 0; ks < 2; ++ks)
          acc[4 + mf][2 + nf] = __builtin_amdgcn_mfma_f32_16x16x32_bf16(fa[mf][ks], fb1[nf][ks], acc[4 + mf][2 + nf], 0, 0, 0);
    __builtin_amdgcn_s_setprio(0);
  }

  // epilogue: D layout col = lane&15, row = (lane>>4)*4 + i
#pragma unroll
  for (int mf = 0; mf < 8; ++mf)
#pragma unroll
    for (int nf = 0; nf < 4; ++nf) {
      const long m = m0 + wm * 128 + ((mf >> 2) * 64) + (mf & 3) * 16 + l16 * 4;
      const long n = n0 + wn * 64 + ((nf >> 1) * 32) + (nf & 1) * 16 + l15;
      const float bv = bias[n];
      if (OUT == 2) {
        const long bb = m >> 11, ss = m & 2047;
        const long head = n >> 7, d = n & 127;
        bf16x4 st;
#pragma unroll
        for (int i = 0; i < 4; ++i) st[i] = (bf16)(acc[mf][nf][i] + bv);
        *(bf16x4*)((bf16*)Cout + ((((bb << 4) + head) << 7) + d) * 2048 + ss) = st;
      } else {
#pragma unroll
        for (int i = 0; i < 4; ++i) {
          float v = acc[mf][nf][i] + bv;
          if (OUT == 1) ((bf16*)Cout)[(m + i) * 2048 + n] = (bf16)v;
          else          ((float*)Cout)[(m + i) * 2048 + n] = v;
        }
      }
    }
}

// ---------------- RoPE in place on [B,S,H,D] bf16 (k only) ----------------
__global__ void rope_kernel(bf16* __restrict__ x, const float* __restrict__ angles,
                            const int* __restrict__ flag, int force)
{
  if (!force && flag[0] == 0) return;
  const int t = threadIdx.x;
  const long R = (long)blockIdx.x * 64 + (t >> 2);
  const int d0 = (t & 3) * 16;
  const long s = (R / Hc) % Sc;
  bf16* rowp = x + R * Dc;
  bf16x8 lo0 = *(bf16x8*)(rowp + d0);
  bf16x8 lo1 = *(bf16x8*)(rowp + d0 + 8);
  bf16x8 hi0 = *(bf16x8*)(rowp + d0 + 64);
  bf16x8 hi1 = *(bf16x8*)(rowp + d0 + 72);
  const float* sp = angles + s * 64 + d0;
  const float* cp = angles + 131072 + s * 64 + d0;
  bf16x8 a0, a1, b0, b1;
#pragma unroll
  for (int j = 0; j < 8; ++j) {
    float c = cp[j], sn = sp[j];
    float x1 = (float)lo0[j], x2 = (float)hi0[j];
    a0[j] = (bf16)(x1 * c - x2 * sn);
    b0[j] = (bf16)(x1 * sn + x2 * c);
    float c1 = cp[j + 8], sn1 = sp[j + 8];
    float y1 = (float)lo1[j], y2 = (float)hi1[j];
    a1[j] = (bf16)(y1 * c1 - y2 * sn1);
    b1[j] = (bf16)(y1 * sn1 + y2 * c1);
  }
  *(bf16x8*)(rowp + d0)      = a0;
  *(bf16x8*)(rowp + d0 + 8)  = a1;
  *(bf16x8*)(rowp + d0 + 64) = b0;
  *(bf16x8*)(rowp + d0 + 72) = b1;
}

// ---------------- Flash attention: r9 body, launch_bounds(256,3) ----------------
// SINGLE CHANGE vs r12: min-waves 2 -> 3. Hypothesis (from r9/r10 occupancy
// pinned at ~2 waves/SIMD despite VGPR_Count 116): the reported count excludes
// the 64 AGPR accumulator (o[4] f32x16); unified-file footprint ~180 -> 2
// waves/SIMD. Cap 170 forces the allocator to shave ~10 regs (mild) -> 3
// waves/SIMD. Spill signature to watch: FETCH >> 100MB.
__global__ __launch_bounds__(256, 3) void attn_kernel(
    const bf16* __restrict__ q0, const bf16* __restrict__ k0,
    const bf16* __restrict__ vt, const int* __restrict__ mask,
    const int* __restrict__ causal_p, const float* __restrict__ angles,
    bf16* __restrict__ attn_out)
{
  __shared__ __align__(16) bf16 Ks[2][64 * 128]; // [kv][d], 16B granule g^(kv&15)
  __shared__ __align__(16) bf16 Vs[128 * 64];    // [d][kv], 16B granule g^(d&7)

  const int tid = threadIdx.x, wid = tid >> 6, lane = tid & 63;
  const int l31 = lane & 31, h = lane >> 5;
  const int id = blockIdx.x;
  const int swz = (id & 7) * 128 + (id >> 3);
  const int bh = swz >> 4, qb = swz & 15;
  const int b = bh >> 4, hh = bh & 15;
  const int q_glob = qb * 128 + wid * 32 + l31;
  const int causal_f = causal_p[0];
  const float SC = 0.08838834764831845f * 1.4426950408889634f; // 1/sqrt(D) * log2(e)
  const float NEG = -3.0e38f;

  auto stageK = [&](int kv0s, int bufs) {
#pragma unroll
    for (int it = 0; it < 4; ++it) {
      int g = it * 256 + tid;
      int r = g >> 4, gp = g & 15;
      async16(k0 + ((size_t)(b * Sc + kv0s + r) * Hc + hh) * Dc + ((gp ^ (r & 15)) << 3),
              &Ks[bufs][g * 8]);
    }
  };
  auto stageV = [&](int kv0s) {
#pragma unroll
    for (int it = 0; it < 4; ++it) {
      int g = it * 256 + tid;
      int r = g >> 3, gp = g & 7;
      async16(vt + ((size_t)bh * Dc + r) * Sc + kv0s + ((gp ^ (r & 7)) << 3),
              &Vs[g * 8]);
    }
  };

  // Q load + RoPE + SC pre-scale, all in registers.
  bf16x8 qf[8];
  {
    const bf16* qrow = q0 + ((size_t)(b * Sc + q_glob) * Hc + hh) * Dc;
#pragma unroll
    for (int dc = 0; dc < 4; ++dc) {
      bf16x8 lo = *(const bf16x8*)(qrow + dc * 16 + h * 8);
      bf16x8 hi = *(const bf16x8*)(qrow + (dc + 4) * 16 + h * 8);
      const float* sp = angles + (size_t)q_glob * 64 + dc * 16 + h * 8;
      union { float4 v[2]; float f[8]; } sn, cs;
      sn.v[0] = ((const float4*)sp)[0];
      sn.v[1] = ((const float4*)sp)[1];
      cs.v[0] = ((const float4*)(sp + 131072))[0];
      cs.v[1] = ((const float4*)(sp + 131072))[1];
#pragma unroll
      for (int j = 0; j < 8; ++j) {
        float x1 = (float)lo[j], x2 = (float)hi[j];
        qf[dc][j]     = (bf16)(SC * (x1 * cs.f[j] - x2 * sn.f[j]));
        qf[dc + 4][j] = (bf16)(SC * (x1 * sn.f[j] + x2 * cs.f[j]));
      }
    }
  }

  f32x16 o[4];
#pragma unroll
  for (int db = 0; db < 4; ++db)
#pragma unroll
    for (int r = 0; r < 16; ++r) o[db][r] = 0.f;
  float mrun = NEG, lrun = 0.f;

  stageK(0, 0);
  const int mv0 = mask[b * Sc + lane];
  asm volatile("s_waitcnt vmcnt(0)" ::: "memory");
  __builtin_amdgcn_s_barrier();
  unsigned long long mbits = __ballot(mv0 != 0);
  int cur = 0;

  for (int kv0 = 0; kv0 < Sc; kv0 += 64) {
    const int kvn = kv0 + 64;
    const bool has_next = (kvn < Sc);
    unsigned long long mbits_next = ~0ull;
    if (has_next) {
      const int mvn = mask[b * Sc + kvn + lane];
      mbits_next = __ballot(mvn != 0);
    }
    stageV(kv0);
    if (has_next) stageK(kvn, cur ^ 1);

    // ================= sub-block 0 (kv rows 0..31) =================
    f32x16 s;
#pragma unroll
    for (int r = 0; r < 16; ++r) s[r] = 0.f;
    __builtin_amdgcn_s_setprio(1);
#pragma unroll
    for (int dc = 0; dc < 8; ++dc) {
      bf16x8 kf = *(const bf16x8*)&Ks[cur][l31 * 128 + (((dc * 2 + h) ^ (l31 & 15)) << 3)];
      s = __builtin_amdgcn_mfma_f32_32x32x16_bf16(kf, qf[dc], s, 0, 0, 0);
    }
    __builtin_amdgcn_s_setprio(0);
    if (mbits != ~0ull) {
#pragma unroll
      for (int r = 0; r < 16; ++r) {
        int off = (r & 3) + 8 * (r >> 2) + 4 * h;
        if (!((mbits >> off) & 1)) s[r] = NEG;
      }
    }
    if (causal_f) {
#pragma unroll
      for (int r = 0; r < 16; ++r) {
        int kvg = kv0 + (r & 3) + 8 * (r >> 2) + 4 * h;
        if (kvg > q_glob) s[r] = NEG;
      }
    }
    {
      float tmax = s[0];
#pragma unroll
      for (int r = 1; r < 16; ++r) tmax = fmaxf(tmax, s[r]);
      tmax = fmaxf(tmax, __shfl_xor(tmax, 32));
      if (!__all(tmax <= mrun + 8.0f)) { // defer-max (T13)
        const float mnew = fmaxf(mrun, tmax);
        const float alpha = __builtin_amdgcn_exp2f(mrun - mnew);
#pragma unroll
        for (int db = 0; db < 4; ++db)
#pragma unroll
          for (int r = 0; r < 16; ++r) o[db][r] *= alpha;
        lrun *= alpha;
        mrun = mnew;
      }
      float rs = 0.f;
#pragma unroll
      for (int r = 0; r < 16; ++r) {
        s[r] = __builtin_amdgcn_exp2f(s[r] - mrun);
        rs += s[r];
      }
      rs += __shfl_xor(rs, 32);
      lrun += rs;
    }
    unsigned int dw0 = pkbf(s[0], s[1]),   dw1 = pkbf(s[2], s[3]);
    unsigned int dw2 = pkbf(s[4], s[5]),   dw3 = pkbf(s[6], s[7]);
    unsigned int dw4 = pkbf(s[8], s[9]),   dw5 = pkbf(s[10], s[11]);
    unsigned int dw6 = pkbf(s[12], s[13]), dw7 = pkbf(s[14], s[15]);
    asm volatile("v_permlane32_swap_b32 %0, %1" : "+v"(dw0), "+v"(dw2));
    asm volatile("v_permlane32_swap_b32 %0, %1" : "+v"(dw1), "+v"(dw3));
    asm volatile("v_permlane32_swap_b32 %0, %1" : "+v"(dw4), "+v"(dw6));
    asm volatile("v_permlane32_swap_b32 %0, %1" : "+v"(dw5), "+v"(dw7));
    union { unsigned int u[4]; bf16x8 v; } pf0, pf1;
    pf0.u[0] = dw0; pf0.u[1] = dw1; pf0.u[2] = dw2; pf0.u[3] = dw3;
    pf1.u[0] = dw4; pf1.u[1] = dw5; pf1.u[2] = dw6; pf1.u[3] = dw7;

    if (has_next) { asm volatile("s_waitcnt vmcnt(4)" ::: "memory"); }
    else          { asm volatile("s_waitcnt vmcnt(0)" ::: "memory"); }
    __builtin_amdgcn_s_barrier();

    __builtin_amdgcn_s_setprio(1);
#pragma unroll
    for (int ksb = 0; ksb < 2; ++ksb) {
      const bf16x8 pfv = ksb ? pf1.v : pf0.v;
#pragma unroll
      for (int db = 0; db < 4; ++db) {
        const int dr = db * 32 + l31;
        bf16x8 vb = *(const bf16x8*)&Vs[dr * 64 + (((ksb * 2 + h) ^ (dr & 7)) << 3)];
        o[db] = __builtin_amdgcn_mfma_f32_32x32x16_bf16(vb, pfv, o[db], 0, 0, 0);
      }
    }
    __builtin_amdgcn_s_setprio(0);

    // ================= sub-block 1 (kv rows 32..63) =================
#pragma unroll
    for (int r = 0; r < 16; ++r) s[r] = 0.f;
    __builtin_amdgcn_s_setprio(1);
#pragma unroll
    for (int dc = 0; dc < 8; ++dc) {
      bf16x8 kf = *(const bf16x8*)&Ks[cur][(32 + l31) * 128 + (((dc * 2 + h) ^ (l31 & 15)) << 3)];
      s = __builtin_amdgcn_mfma_f32_32x32x16_bf16(kf, qf[dc], s, 0, 0, 0);
    }
    __builtin_amdgcn_s_setprio(0);
    if (mbits != ~0ull) {
#pragma unroll
      for (int r = 0; r < 16; ++r) {
        int off = 32 + (r & 3) + 8 * (r >> 2) + 4 * h;
        if (!((mbits >> off) & 1)) s[r] = NEG;
      }
    }
    if (causal_f) {
#pragma unroll
      for (int r = 0; r < 16; ++r) {
        int kvg = kv0 + 32 + (r & 3) + 8 * (r >> 2) + 4 * h;
        if (kvg > q_glob) s[r] = NEG;
      }
    }
    {
      float tmax = s[0];
#pragma unroll
      for (int r = 1; r < 16; ++r) tmax = fmaxf(tmax, s[r]);
      tmax = fmaxf(tmax, __shfl_xor(tmax, 32));
      if (!__all(tmax <= mrun + 8.0f)) {
        const float mnew = fmaxf(mrun, tmax);
        const float alpha = __builtin_amdgcn_exp2f(mrun - mnew);
#pragma unroll
        for (int db = 0; db < 4; ++db)
#pragma unroll
          for (int r = 0; r < 16; ++r) o[db][r] *= alpha;
        lrun *= alpha;
        mrun = mnew;
      }
      float rs = 0.f;
#pragma unroll
      for (int r = 0; r < 16; ++r) {
        s[r] = __builtin_amdgcn_exp2f(s[r] - mrun);
        rs += s[r];
      }
      rs += __shfl_xor(rs, 32);
      lrun += rs;
    }
    dw0 = pkbf(s[0], s[1]);   dw1 = pkbf(s[2], s[3]);
    dw2 = pkbf(s[4], s[5]);   dw3 = pkbf(s[6], s[7]);
    dw4 = pkbf(s[8], s[9]);   dw5 = pkbf(s[10], s[11]);
    dw6 = pkbf(s[12], s[13]); dw7 = pkbf(s[14], s[15]);
    asm volatile("v_permlane32_swap_b32 %0, %1" : "+v"(dw0), "+v"(dw2));
    asm volatile("v_permlane32_swap_b32 %0, %1" : "+v"(dw1), "+v"(dw3));
    asm volatile("v_permlane32_swap_b32 %0, %1" : "+v"(dw4), "+v"(dw6));
    asm volatile("v_permlane32_swap_b32 %0, %1" : "+v"(dw5), "+v"(dw7));
    pf0.u[0] = dw0; pf0.u[1] = dw1; pf0.u[2] = dw2; pf0.u[3] = dw3;
    pf1.u[0] = dw4; pf1.u[1] = dw5; pf1.u[2] = dw6; pf1.u[3] = dw7;

    __builtin_amdgcn_s_setprio(1);
#pragma unroll
    for (int ksb = 0; ksb < 2; ++ksb) {
      const bf16x8 pfv = ksb ? pf1.v : pf0.v;
#pragma unroll
      for (int db = 0; db < 4; ++db) {
        const int dr = db * 32 + l31;
        bf16x8 vb = *(const bf16x8*)&Vs[dr * 64 + ((((2 + ksb) * 2 + h) ^ (dr & 7)) << 3)];
        o[db] = __builtin_amdgcn_mfma_f32_32x32x16_bf16(vb, pfv, o[db], 0, 0, 0);
      }
    }
    __builtin_amdgcn_s_setprio(0);

    asm volatile("s_waitcnt vmcnt(0)" ::: "memory");
    __builtin_amdgcn_s_barrier();
    cur ^= 1;
    mbits = mbits_next;
  }

  // epilogue: lane owns row q_glob, d = db*32 + 8*rq + 4*h + i
  const float inv = 1.0f / lrun;
  bf16* orow = attn_out + ((size_t)(b * Sc + q_glob) * Hc + hh) * Dc;
#pragma unroll
  for (int db = 0; db < 4; ++db)
#pragma unroll
    for (int rq = 0; rq < 4; ++rq) {
      bf16x4 st;
#pragma unroll
      for (int i = 0; i < 4; ++i) st[i] = (bf16)(o[db][rq * 4 + i] * inv);
      *(bf16x4*)(orow + db * 32 + rq * 8 + 4 * h) = st;
    }
}

// ---------------- host ----------------
extern "C" void kernel_launch(void* const* d_in, const int* in_sizes, int n_in,
                              void* d_out, int out_size, void* d_ws, size_t ws_size,
                              hipStream_t stream)
{
  const float* x_q    = (const float*)d_in[0];
  const float* x_kv   = (const float*)d_in[1];
  const float* Wq     = (const float*)d_in[2];
  const float* bq     = (const float*)d_in[3];
  const float* Wk     = (const float*)d_in[4];
  const float* bk     = (const float*)d_in[5];
  const float* Wv     = (const float*)d_in[6];
  const float* bv     = (const float*)d_in[7];
  const float* Wo     = (const float*)d_in[8];
  const float* bo     = (const float*)d_in[9];
  const float* angles = (const float*)d_in[10];
  const int*   amask  = (const int*)d_in[11];
  const int*   causal = (const int*)d_in[12];
  const int*   k_rope = (const int*)d_in[13];
  float* out = (float*)d_out;

  char* ws = (char*)d_ws;
  const size_t MB32 = (size_t)33554432;
  bf16* xq16  = (bf16*)(ws);
  bf16* xkv16 = (bf16*)(ws + MB32);
  bf16* wq16  = (bf16*)(ws + 2 * MB32);
  bf16* wk16  = wq16 + 4194304;
  bf16* wv16  = wk16 + 4194304;
  bf16* wo16  = wv16 + 4194304;
  bf16* q0    = (bf16*)(ws + 3 * MB32);
  bf16* k0    = (bf16*)(ws + 4 * MB32);
  bf16* Vt     = xq16;   // xq16 dead after q-projection; V-GEMM writes Vt directly
  bf16* attn16 = xkv16;  // xkv16 dead after k/v-projections

  cvt_multi<<<dim3(1024, 2), 256, 0, stream>>>(x_q, x_kv, x_q, x_kv,
                                               xq16, xkv16, xq16, xkv16, Mc * Ec / 8);
  cvt_multi<<<dim3(256, 4), 256, 0, stream>>>(Wq, Wk, Wv, Wo,
                                              wq16, wk16, wv16, wo16, Ec * Ec / 8);

  const int gemmBlocks = (Mc / 256) * (Ec / 256); // 256
  gemm8<1><<<gemmBlocks, 512, 0, stream>>>(xq16,  wq16, bq, q0, Mc / 256);
  gemm8<1><<<gemmBlocks, 512, 0, stream>>>(xkv16, wk16, bk, k0, Mc / 256);
  gemm8<2><<<gemmBlocks, 512, 0, stream>>>(xkv16, wv16, bv, Vt, Mc / 256); // fused transpose

  rope_kernel<<<2048, 256, 0, stream>>>(k0, angles, k_rope, 0); // k only (gated)

  attn_kernel<<<1024, 256, 0, stream>>>(q0, k0, Vt, amask, causal, angles, attn16);

  gemm8<0><<<gemmBlocks, 512, 0, stream>>>(attn16, wo16, bo, out, Mc / 256);
}

// Round 15
// 473.515 us; speedup vs baseline: 1.7570x; 1.7570x over previous
//
#include <hip/hip_runtime.h>
#include <hip/hip_bf16.h>

// Fused MHA+RoPE pipeline for MI355X (gfx950), bf16 MFMA throughout.
// B=4, S=2048, E=2048, H=16, D=128, M=B*S=8192.
//
// ws layout (192 MB):
//   [0,32M)    xq16
//   [32,64M)   xkv16 -> later reused as attn16 [M][E]
//   [64,96M)   wq16,wk16,wv16,wo16 (8MB each)
//   [96,128M)  q0   [128,160M) k0   [160,192M) Vt [BH][D][S]

typedef __bf16 bf16;
typedef __bf16 bf16x8 __attribute__((ext_vector_type(8)));
typedef __bf16 bf16x4 __attribute__((ext_vector_type(4)));
typedef __bf16 bf16x2 __attribute__((ext_vector_type(2)));
typedef float  f32x4  __attribute__((ext_vector_type(4)));
typedef float  f32x16 __attribute__((ext_vector_type(16)));

constexpr int Bc = 4, Sc = 2048, Ec = 2048, Hc = 16, Dc = 128;
constexpr int Mc = Bc * Sc; // 8192

__device__ __forceinline__ void async16(const void* g, void* l) {
  __builtin_amdgcn_global_load_lds(
      (const __attribute__((address_space(1))) void*)g,
      (__attribute__((address_space(3))) void*)l, 16, 0, 0);
}

__device__ __forceinline__ unsigned int pkbf(float a, float b) {
  union { bf16x2 v; unsigned int u; } c;
  c.v[0] = (bf16)a; c.v[1] = (bf16)b;
  return c.u;
}

// ---------------- fp32 -> bf16 convert (6 jobs, one launch) ----------------
__global__ void cvt_multi6(const float* s0, const float* s1, const float* s2,
                           const float* s3, const float* s4, const float* s5,
                           bf16* d0, bf16* d1, bf16* d2, bf16* d3, bf16* d4, bf16* d5,
                           int n8x, int n8w) {
  const float* src; bf16* dst; int n8;
  switch (blockIdx.y) {
    case 0:  src = s0; dst = d0; n8 = n8x; break;
    case 1:  src = s1; dst = d1; n8 = n8x; break;
    case 2:  src = s2; dst = d2; n8 = n8w; break;
    case 3:  src = s3; dst = d3; n8 = n8w; break;
    case 4:  src = s4; dst = d4; n8 = n8w; break;
    default: src = s5; dst = d5; n8 = n8w; break;
  }
  int i = blockIdx.x * blockDim.x + threadIdx.x;
  const int stride = gridDim.x * blockDim.x;
  for (; i < n8; i += stride) {
    const float4 a = *((const float4*)src + (size_t)i * 2);
    const float4 b = *((const float4*)src + (size_t)i * 2 + 1);
    bf16x8 o;
    o[0] = (bf16)a.x; o[1] = (bf16)a.y; o[2] = (bf16)a.z; o[3] = (bf16)a.w;
    o[4] = (bf16)b.x; o[5] = (bf16)b.y; o[6] = (bf16)b.z; o[7] = (bf16)b.w;
    *(bf16x8*)(dst + (size_t)i * 8) = o;
  }
}

// ---------------- GEMM: C[m][n] = sum_k A[m][k]*B[n][k] + bias[n] ----------------
// 8-phase structure with r12's PROVEN wait algebra (each phase's LDS reads are
// certified by a wait executed in the PREVIOUS phase, before the barrier):
//   prologue: vmcnt(4)                       [A0(0),B0(0) resident]
//   ph0: read A0,B0; vmcnt(2); barrier; MFMA  [certifies B1(t) for ph1]
//   ph1: read B1; stage A0',B0'; vmcnt(4|0); barrier; MFMA  [certifies A1(t)]
//   ph2: read A1; stage B1'; barrier; MFMA
//   ph3: stage A1'; vmcnt(4); barrier; MFMA   [certifies A0',B0' for next ph0]
// r14's "relaxed" variant put waits AFTER the dependent reads -> race (absmax
// 1.4e-2). Reverted. r14's safe changes kept: runtime job select (QKV as one
// dispatch) and merged cvt.
// omode: 0 = f32 linear, 1 = bf16 linear, 2 = bf16 transposed into Vt[bh][d][s].
__global__ __launch_bounds__(512, 2) void gemm8(
    const bf16* __restrict__ Aq, const bf16* __restrict__ Akv,
    const bf16* __restrict__ B0p, const bf16* __restrict__ B1p, const bf16* __restrict__ B2p,
    const float* __restrict__ bi0, const float* __restrict__ bi1, const float* __restrict__ bi2,
    void* __restrict__ C0p, void* __restrict__ C1p, void* __restrict__ C2p,
    int md0, int md1, int md2, int Mblocks)
{
  __shared__ __align__(16) bf16 lds[2 * 32768]; // 128KB
  const int job = blockIdx.y;
  const bf16* A  = (job == 0) ? Aq : Akv;
  const bf16* Bm = (job == 0) ? B0p : (job == 1) ? B1p : B2p;
  const float* bias = (job == 0) ? bi0 : (job == 1) ? bi1 : bi2;
  void* Cout = (job == 0) ? C0p : (job == 1) ? C1p : C2p;
  const int omode = (job == 0) ? md0 : (job == 1) ? md1 : md2;

  const int tid = threadIdx.x;
  const int w = tid >> 6, lane = tid & 63;
  const int l15 = lane & 15, l16 = lane >> 4;
  const int wm = w >> 2, wn = w & 3;
  const int id = blockIdx.x;
  const int nwg = Mblocks * 8, cpx = nwg >> 3;
  const int swz = (id & 7) * cpx + (id >> 3);
  const int by = swz >> 3, bx = swz & 7;
  const long m0 = (long)by * 256, n0 = (long)bx * 256;
  constexpr int NT = 32; // K/64

  auto stA = [&](int buf, long kt, int p, int j) {
    int ca = p + 2 * j;
    int row = ca * 64 + (tid >> 3);
    async16(A + (m0 + row) * 2048 + kt + (((tid & 7) ^ (row & 7)) << 3),
            &lds[buf * 32768 + ca * 4096 + tid * 8]);
  };
  auto stB = [&](int buf, long kt, int p, int j) {
    int cb = p + 4 * j + 2 * (tid >> 8);
    int row = cb * 32 + ((tid & 255) >> 3);
    async16(Bm + (n0 + row) * 2048 + kt + (((tid & 7) ^ (row & 7)) << 3),
            &lds[buf * 32768 + 16384 + (p + 4 * j) * 2048 + (tid >> 8) * 4096 + (tid & 255) * 8]);
  };

  f32x4 acc[8][4];
#pragma unroll
  for (int a = 0; a < 8; ++a)
#pragma unroll
    for (int b = 0; b < 4; ++b) acc[a][b] = f32x4{0.f, 0.f, 0.f, 0.f};

  // prologue: tile 0 in issue order A0, B0, B1, A1 (matches steady state).
  stA(0, 0, 0, 0); stA(0, 0, 0, 1);
  stB(0, 0, 0, 0); stB(0, 0, 0, 1);
  stB(0, 0, 1, 0); stB(0, 0, 1, 1);
  stA(0, 0, 1, 0); stA(0, 0, 1, 1);
  asm volatile("s_waitcnt vmcnt(4)" ::: "memory"); // A0(0),B0(0) resident
  __builtin_amdgcn_s_barrier();

  for (int t = 0; t < NT; ++t) {
    const int buf = t & 1, nbuf = buf ^ 1;
    const int base = buf * 32768;
    const long ktn = (long)(t + 1) * 64;
    const bool pf = (t < NT - 1);
    bf16x8 fa[4][2], fb0[2][2], fb1[2][2];

    // ---- phase 0: quadrant (mh0, nh0) ----
#pragma unroll
    for (int mf = 0; mf < 4; ++mf)
#pragma unroll
      for (int ks = 0; ks < 2; ++ks) {
        int row = wm * 128 + mf * 16 + l15;
        fa[mf][ks] = *(const bf16x8*)&lds[base + row * 64 + (((ks * 4 + l16) ^ (row & 7)) << 3)];
      }
#pragma unroll
    for (int nf = 0; nf < 2; ++nf)
#pragma unroll
      for (int ks = 0; ks < 2; ++ks) {
        int row = wn * 64 + nf * 16 + l15;
        fb0[nf][ks] = *(const bf16x8*)&lds[base + 16384 + row * 64 + (((ks * 4 + l16) ^ (row & 7)) << 3)];
      }
    asm volatile("s_waitcnt vmcnt(2)" ::: "memory"); // certifies B1(t) for ph1
    asm volatile("" ::: "memory");
    __builtin_amdgcn_s_barrier();
    __builtin_amdgcn_s_setprio(1);
#pragma unroll
    for (int mf = 0; mf < 4; ++mf)
#pragma unroll
      for (int nf = 0; nf < 2; ++nf)
#pragma unroll
        for (int ks = 0; ks < 2; ++ks)
          acc[mf][nf] = __builtin_amdgcn_mfma_f32_16x16x32_bf16(fa[mf][ks], fb0[nf][ks], acc[mf][nf], 0, 0, 0);
    __builtin_amdgcn_s_setprio(0);

    // ---- phase 1: quadrant (mh0, nh1); stage A0(t+1), B0(t+1) ----
#pragma unroll
    for (int nf = 0; nf < 2; ++nf)
#pragma unroll
      for (int ks = 0; ks < 2; ++ks) {
        int row = wn * 64 + 32 + nf * 16 + l15;
        fb1[nf][ks] = *(const bf16x8*)&lds[base + 16384 + row * 64 + (((ks * 4 + l16) ^ (row & 7)) << 3)];
      }
    if (pf) { stA(nbuf, ktn, 0, 0); stA(nbuf, ktn, 0, 1); stB(nbuf, ktn, 0, 0); stB(nbuf, ktn, 0, 1); }
    if (pf) { asm volatile("s_waitcnt vmcnt(4)" ::: "memory"); } // certifies A1(t) for ph2
    else    { asm volatile("s_waitcnt vmcnt(0)" ::: "memory"); }
    asm volatile("" ::: "memory");
    __builtin_amdgcn_s_barrier();
    __builtin_amdgcn_s_setprio(1);
#pragma unroll
    for (int mf = 0; mf < 4; ++mf)
#pragma unroll
      for (int nf = 0; nf < 2; ++nf)
#pragma unroll
        for (int ks = 0; ks < 2; ++ks)
          acc[mf][2 + nf] = __builtin_amdgcn_mfma_f32_16x16x32_bf16(fa[mf][ks], fb1[nf][ks], acc[mf][2 + nf], 0, 0, 0);
    __builtin_amdgcn_s_setprio(0);

    // ---- phase 2: quadrant (mh1, nh0); stage B1(t+1) ----
#pragma unroll
    for (int mf = 0; mf < 4; ++mf)
#pragma unroll
      for (int ks = 0; ks < 2; ++ks) {
        int row = wm * 128 + 64 + mf * 16 + l15;
        fa[mf][ks] = *(const bf16x8*)&lds[base + row * 64 + (((ks * 4 + l16) ^ (row & 7)) << 3)];
      }
    if (pf) { stB(nbuf, ktn, 1, 0); stB(nbuf, ktn, 1, 1); }
    asm volatile("" ::: "memory");
    __builtin_amdgcn_s_barrier();
    __builtin_amdgcn_s_setprio(1);
#pragma unroll
    for (int mf = 0; mf < 4; ++mf)
#pragma unroll
      for (int nf = 0; nf < 2; ++nf)
#pragma unroll
        for (int ks = 0; ks < 2; ++ks)
          acc[4 + mf][nf] = __builtin_amdgcn_mfma_f32_16x16x32_bf16(fa[mf][ks], fb0[nf][ks], acc[4 + mf][nf], 0, 0, 0);
    __builtin_amdgcn_s_setprio(0);

    // ---- phase 3: quadrant (mh1, nh1); stage A1(t+1); vmcnt(4) certifies next ph0 ----
    if (pf) {
      stA(nbuf, ktn, 1, 0); stA(nbuf, ktn, 1, 1);
      asm volatile("s_waitcnt vmcnt(4)" ::: "memory"); // A0(t+1),B0(t+1) resident
    }
    asm volatile("" ::: "memory");
    __builtin_amdgcn_s_barrier();
    __builtin_amdgcn_s_setprio(1);
#pragma unroll
    for (int mf = 0; mf < 4; ++mf)
#pragma unroll
      for (int nf = 0; nf < 2; ++nf)
#pragma unroll
        for (int ks = 0; ks < 2; ++ks)
          acc[4 + mf][2 + nf] = __builtin_amdgcn_mfma_f32_16x16x32_bf16(fa[mf][ks], fb1[nf][ks], acc[4 + mf][2 + nf], 0, 0, 0);
    __builtin_amdgcn_s_setprio(0);
  }

  // epilogue: D layout col = lane&15, row = (lane>>4)*4 + i
#pragma unroll
  for (int mf = 0; mf < 8; ++mf)
#pragma unroll
    for (int nf = 0; nf < 4; ++nf) {
      const long m = m0 + wm * 128 + ((mf >> 2) * 64) + (mf & 3) * 16 + l16 * 4;
      const long n = n0 + wn * 64 + ((nf >> 1) * 32) + (nf & 1) * 16 + l15;
      const float bv = bias[n];
      if (omode == 2) {
        // V-transpose epilogue: Vt[(b*16+head)*128 + d][s], s = m%2048
        const long bb = m >> 11, ss = m & 2047;
        const long head = n >> 7, d = n & 127;
        bf16x4 st;
#pragma unroll
        for (int i = 0; i < 4; ++i) st[i] = (bf16)(acc[mf][nf][i] + bv);
        *(bf16x4*)((bf16*)Cout + ((((bb << 4) + head) << 7) + d) * 2048 + ss) = st;
      } else if (omode == 1) {
#pragma unroll
        for (int i = 0; i < 4; ++i)
          ((bf16*)Cout)[(m + i) * 2048 + n] = (bf16)(acc[mf][nf][i] + bv);
      } else {
#pragma unroll
        for (int i = 0; i < 4; ++i)
          ((float*)Cout)[(m + i) * 2048 + n] = acc[mf][nf][i] + bv;
      }
    }
}

// ---------------- RoPE in place on [B,S,H,D] bf16 (k only) ----------------
__global__ void rope_kernel(bf16* __restrict__ x, const float* __restrict__ angles,
                            const int* __restrict__ flag, int force)
{
  if (!force && flag[0] == 0) return;
  const int t = threadIdx.x;
  const long R = (long)blockIdx.x * 64 + (t >> 2);
  const int d0 = (t & 3) * 16;
  const long s = (R / Hc) % Sc;
  bf16* rowp = x + R * Dc;
  bf16x8 lo0 = *(bf16x8*)(rowp + d0);
  bf16x8 lo1 = *(bf16x8*)(rowp + d0 + 8);
  bf16x8 hi0 = *(bf16x8*)(rowp + d0 + 64);
  bf16x8 hi1 = *(bf16x8*)(rowp + d0 + 72);
  const float* sp = angles + s * 64 + d0;
  const float* cp = angles + 131072 + s * 64 + d0;
  bf16x8 a0, a1, b0, b1;
#pragma unroll
  for (int j = 0; j < 8; ++j) {
    float c = cp[j], sn = sp[j];
    float x1 = (float)lo0[j], x2 = (float)hi0[j];
    a0[j] = (bf16)(x1 * c - x2 * sn);
    b0[j] = (bf16)(x1 * sn + x2 * c);
    float c1 = cp[j + 8], sn1 = sp[j + 8];
    float y1 = (float)lo1[j], y2 = (float)hi1[j];
    a1[j] = (bf16)(y1 * c1 - y2 * sn1);
    b1[j] = (bf16)(y1 * sn1 + y2 * c1);
  }
  *(bf16x8*)(rowp + d0)      = a0;
  *(bf16x8*)(rowp + d0 + 8)  = a1;
  *(bf16x8*)(rowp + d0 + 64) = b0;
  *(bf16x8*)(rowp + d0 + 72) = b1;
}

// ---------------- Flash attention (r9/r12 verbatim — proven best, 190us) ----------------
__global__ __launch_bounds__(256, 2) void attn_kernel(
    const bf16* __restrict__ q0, const bf16* __restrict__ k0,
    const bf16* __restrict__ vt, const int* __restrict__ mask,
    const int* __restrict__ causal_p, const float* __restrict__ angles,
    bf16* __restrict__ attn_out)
{
  __shared__ __align__(16) bf16 Ks[2][64 * 128]; // [kv][d], 16B granule g^(kv&15)
  __shared__ __align__(16) bf16 Vs[128 * 64];    // [d][kv], 16B granule g^(d&7)

  const int tid = threadIdx.x, wid = tid >> 6, lane = tid & 63;
  const int l31 = lane & 31, h = lane >> 5;
  const int id = blockIdx.x;
  const int swz = (id & 7) * 128 + (id >> 3);
  const int bh = swz >> 4, qb = swz & 15;
  const int b = bh >> 4, hh = bh & 15;
  const int q_glob = qb * 128 + wid * 32 + l31;
  const int causal_f = causal_p[0];
  const float SC = 0.08838834764831845f * 1.4426950408889634f; // 1/sqrt(D) * log2(e)
  const float NEG = -3.0e38f;

  auto stageK = [&](int kv0s, int bufs) {
#pragma unroll
    for (int it = 0; it < 4; ++it) {
      int g = it * 256 + tid;
      int r = g >> 4, gp = g & 15;
      async16(k0 + ((size_t)(b * Sc + kv0s + r) * Hc + hh) * Dc + ((gp ^ (r & 15)) << 3),
              &Ks[bufs][g * 8]);
    }
  };
  auto stageV = [&](int kv0s) {
#pragma unroll
    for (int it = 0; it < 4; ++it) {
      int g = it * 256 + tid;
      int r = g >> 3, gp = g & 7;
      async16(vt + ((size_t)bh * Dc + r) * Sc + kv0s + ((gp ^ (r & 7)) << 3),
              &Vs[g * 8]);
    }
  };

  // Q load + RoPE + SC pre-scale, all in registers.
  bf16x8 qf[8];
  {
    const bf16* qrow = q0 + ((size_t)(b * Sc + q_glob) * Hc + hh) * Dc;
#pragma unroll
    for (int dc = 0; dc < 4; ++dc) {
      bf16x8 lo = *(const bf16x8*)(qrow + dc * 16 + h * 8);
      bf16x8 hi = *(const bf16x8*)(qrow + (dc + 4) * 16 + h * 8);
      const float* sp = angles + (size_t)q_glob * 64 + dc * 16 + h * 8;
      union { float4 v[2]; float f[8]; } sn, cs;
      sn.v[0] = ((const float4*)sp)[0];
      sn.v[1] = ((const float4*)sp)[1];
      cs.v[0] = ((const float4*)(sp + 131072))[0];
      cs.v[1] = ((const float4*)(sp + 131072))[1];
#pragma unroll
      for (int j = 0; j < 8; ++j) {
        float x1 = (float)lo[j], x2 = (float)hi[j];
        qf[dc][j]     = (bf16)(SC * (x1 * cs.f[j] - x2 * sn.f[j]));
        qf[dc + 4][j] = (bf16)(SC * (x1 * sn.f[j] + x2 * cs.f[j]));
      }
    }
  }

  f32x16 o[4];
#pragma unroll
  for (int db = 0; db < 4; ++db)
#pragma unroll
    for (int r = 0; r < 16; ++r) o[db][r] = 0.f;
  float mrun = NEG, lrun = 0.f;

  stageK(0, 0);
  const int mv0 = mask[b * Sc + lane];
  asm volatile("s_waitcnt vmcnt(0)" ::: "memory");
  __builtin_amdgcn_s_barrier();
  unsigned long long mbits = __ballot(mv0 != 0);
  int cur = 0;

  for (int kv0 = 0; kv0 < Sc; kv0 += 64) {
    const int kvn = kv0 + 64;
    const bool has_next = (kvn < Sc);
    unsigned long long mbits_next = ~0ull;
    if (has_next) {
      const int mvn = mask[b * Sc + kvn + lane];
      mbits_next = __ballot(mvn != 0);
    }
    stageV(kv0);
    if (has_next) stageK(kvn, cur ^ 1);

    // ================= sub-block 0 (kv rows 0..31) =================
    f32x16 s;
#pragma unroll
    for (int r = 0; r < 16; ++r) s[r] = 0.f;
    __builtin_amdgcn_s_setprio(1);
#pragma unroll
    for (int dc = 0; dc < 8; ++dc) {
      bf16x8 kf = *(const bf16x8*)&Ks[cur][l31 * 128 + (((dc * 2 + h) ^ (l31 & 15)) << 3)];
      s = __builtin_amdgcn_mfma_f32_32x32x16_bf16(kf, qf[dc], s, 0, 0, 0);
    }
    __builtin_amdgcn_s_setprio(0);
    if (mbits != ~0ull) {
#pragma unroll
      for (int r = 0; r < 16; ++r) {
        int off = (r & 3) + 8 * (r >> 2) + 4 * h;
        if (!((mbits >> off) & 1)) s[r] = NEG;
      }
    }
    if (causal_f) {
#pragma unroll
      for (int r = 0; r < 16; ++r) {
        int kvg = kv0 + (r & 3) + 8 * (r >> 2) + 4 * h;
        if (kvg > q_glob) s[r] = NEG;
      }
    }
    {
      float tmax = s[0];
#pragma unroll
      for (int r = 1; r < 16; ++r) tmax = fmaxf(tmax, s[r]);
      tmax = fmaxf(tmax, __shfl_xor(tmax, 32));
      if (!__all(tmax <= mrun + 8.0f)) { // defer-max (T13)
        const float mnew = fmaxf(mrun, tmax);
        const float alpha = __builtin_amdgcn_exp2f(mrun - mnew);
#pragma unroll
        for (int db = 0; db < 4; ++db)
#pragma unroll
          for (int r = 0; r < 16; ++r) o[db][r] *= alpha;
        lrun *= alpha;
        mrun = mnew;
      }
      float rs = 0.f;
#pragma unroll
      for (int r = 0; r < 16; ++r) {
        s[r] = __builtin_amdgcn_exp2f(s[r] - mrun);
        rs += s[r];
      }
      rs += __shfl_xor(rs, 32);
      lrun += rs;
    }
    unsigned int dw0 = pkbf(s[0], s[1]),   dw1 = pkbf(s[2], s[3]);
    unsigned int dw2 = pkbf(s[4], s[5]),   dw3 = pkbf(s[6], s[7]);
    unsigned int dw4 = pkbf(s[8], s[9]),   dw5 = pkbf(s[10], s[11]);
    unsigned int dw6 = pkbf(s[12], s[13]), dw7 = pkbf(s[14], s[15]);
    asm volatile("v_permlane32_swap_b32 %0, %1" : "+v"(dw0), "+v"(dw2));
    asm volatile("v_permlane32_swap_b32 %0, %1" : "+v"(dw1), "+v"(dw3));
    asm volatile("v_permlane32_swap_b32 %0, %1" : "+v"(dw4), "+v"(dw6));
    asm volatile("v_permlane32_swap_b32 %0, %1" : "+v"(dw5), "+v"(dw7));
    union { unsigned int u[4]; bf16x8 v; } pf0, pf1;
    pf0.u[0] = dw0; pf0.u[1] = dw1; pf0.u[2] = dw2; pf0.u[3] = dw3;
    pf1.u[0] = dw4; pf1.u[1] = dw5; pf1.u[2] = dw6; pf1.u[3] = dw7;

    if (has_next) { asm volatile("s_waitcnt vmcnt(4)" ::: "memory"); }
    else          { asm volatile("s_waitcnt vmcnt(0)" ::: "memory"); }
    __builtin_amdgcn_s_barrier();

    __builtin_amdgcn_s_setprio(1);
#pragma unroll
    for (int ksb = 0; ksb < 2; ++ksb) {
      const bf16x8 pfv = ksb ? pf1.v : pf0.v;
#pragma unroll
      for (int db = 0; db < 4; ++db) {
        const int dr = db * 32 + l31;
        bf16x8 vb = *(const bf16x8*)&Vs[dr * 64 + (((ksb * 2 + h) ^ (dr & 7)) << 3)];
        o[db] = __builtin_amdgcn_mfma_f32_32x32x16_bf16(vb, pfv, o[db], 0, 0, 0);
      }
    }
    __builtin_amdgcn_s_setprio(0);

    // ================= sub-block 1 (kv rows 32..63) =================
#pragma unroll
    for (int r = 0; r < 16; ++r) s[r] = 0.f;
    __builtin_amdgcn_s_setprio(1);
#pragma unroll
    for (int dc = 0; dc < 8; ++dc) {
      bf16x8 kf = *(const bf16x8*)&Ks[cur][(32 + l31) * 128 + (((dc * 2 + h) ^ (l31 & 15)) << 3)];
      s = __builtin_amdgcn_mfma_f32_32x32x16_bf16(kf, qf[dc], s, 0, 0, 0);
    }
    __builtin_amdgcn_s_setprio(0);
    if (mbits != ~0ull) {
#pragma unroll
      for (int r = 0; r < 16; ++r) {
        int off = 32 + (r & 3) + 8 * (r >> 2) + 4 * h;
        if (!((mbits >> off) & 1)) s[r] = NEG;
      }
    }
    if (causal_f) {
#pragma unroll
      for (int r = 0; r < 16; ++r) {
        int kvg = kv0 + 32 + (r & 3) + 8 * (r >> 2) + 4 * h;
        if (kvg > q_glob) s[r] = NEG;
      }
    }
    {
      float tmax = s[0];
#pragma unroll
      for (int r = 1; r < 16; ++r) tmax = fmaxf(tmax, s[r]);
      tmax = fmaxf(tmax, __shfl_xor(tmax, 32));
      if (!__all(tmax <= mrun + 8.0f)) {
        const float mnew = fmaxf(mrun, tmax);
        const float alpha = __builtin_amdgcn_exp2f(mrun - mnew);
#pragma unroll
        for (int db = 0; db < 4; ++db)
#pragma unroll
          for (int r = 0; r < 16; ++r) o[db][r] *= alpha;
        lrun *= alpha;
        mrun = mnew;
      }
      float rs = 0.f;
#pragma unroll
      for (int r = 0; r < 16; ++r) {
        s[r] = __builtin_amdgcn_exp2f(s[r] - mrun);
        rs += s[r];
      }
      rs += __shfl_xor(rs, 32);
      lrun += rs;
    }
    dw0 = pkbf(s[0], s[1]);   dw1 = pkbf(s[2], s[3]);
    dw2 = pkbf(s[4], s[5]);   dw3 = pkbf(s[6], s[7]);
    dw4 = pkbf(s[8], s[9]);   dw5 = pkbf(s[10], s[11]);
    dw6 = pkbf(s[12], s[13]); dw7 = pkbf(s[14], s[15]);
    asm volatile("v_permlane32_swap_b32 %0, %1" : "+v"(dw0), "+v"(dw2));
    asm volatile("v_permlane32_swap_b32 %0, %1" : "+v"(dw1), "+v"(dw3));
    asm volatile("v_permlane32_swap_b32 %0, %1" : "+v"(dw4), "+v"(dw6));
    asm volatile("v_permlane32_swap_b32 %0, %1" : "+v"(dw5), "+v"(dw7));
    pf0.u[0] = dw0; pf0.u[1] = dw1; pf0.u[2] = dw2; pf0.u[3] = dw3;
    pf1.u[0] = dw4; pf1.u[1] = dw5; pf1.u[2] = dw6; pf1.u[3] = dw7;

    __builtin_amdgcn_s_setprio(1);
#pragma unroll
    for (int ksb = 0; ksb < 2; ++ksb) {
      const bf16x8 pfv = ksb ? pf1.v : pf0.v;
#pragma unroll
      for (int db = 0; db < 4; ++db) {
        const int dr = db * 32 + l31;
        bf16x8 vb = *(const bf16x8*)&Vs[dr * 64 + ((((2 + ksb) * 2 + h) ^ (dr & 7)) << 3)];
        o[db] = __builtin_amdgcn_mfma_f32_32x32x16_bf16(vb, pfv, o[db], 0, 0, 0);
      }
    }
    __builtin_amdgcn_s_setprio(0);

    asm volatile("s_waitcnt vmcnt(0)" ::: "memory");
    __builtin_amdgcn_s_barrier();
    cur ^= 1;
    mbits = mbits_next;
  }

  // epilogue: lane owns row q_glob, d = db*32 + 8*rq + 4*h + i
  const float inv = 1.0f / lrun;
  bf16* orow = attn_out + ((size_t)(b * Sc + q_glob) * Hc + hh) * Dc;
#pragma unroll
  for (int db = 0; db < 4; ++db)
#pragma unroll
    for (int rq = 0; rq < 4; ++rq) {
      bf16x4 st;
#pragma unroll
      for (int i = 0; i < 4; ++i) st[i] = (bf16)(o[db][rq * 4 + i] * inv);
      *(bf16x4*)(orow + db * 32 + rq * 8 + 4 * h) = st;
    }
}

// ---------------- host ----------------
extern "C" void kernel_launch(void* const* d_in, const int* in_sizes, int n_in,
                              void* d_out, int out_size, void* d_ws, size_t ws_size,
                              hipStream_t stream)
{
  const float* x_q    = (const float*)d_in[0];
  const float* x_kv   = (const float*)d_in[1];
  const float* Wq     = (const float*)d_in[2];
  const float* bq     = (const float*)d_in[3];
  const float* Wk     = (const float*)d_in[4];
  const float* bk     = (const float*)d_in[5];
  const float* Wv     = (const float*)d_in[6];
  const float* bv     = (const float*)d_in[7];
  const float* Wo     = (const float*)d_in[8];
  const float* bo     = (const float*)d_in[9];
  const float* angles = (const float*)d_in[10];
  const int*   amask  = (const int*)d_in[11];
  const int*   causal = (const int*)d_in[12];
  const int*   k_rope = (const int*)d_in[13];
  float* out = (float*)d_out;

  char* ws = (char*)d_ws;
  const size_t MB32 = (size_t)33554432;
  bf16* xq16  = (bf16*)(ws);
  bf16* xkv16 = (bf16*)(ws + MB32);
  bf16* wq16  = (bf16*)(ws + 2 * MB32);
  bf16* wk16  = wq16 + 4194304;
  bf16* wv16  = wk16 + 4194304;
  bf16* wo16  = wv16 + 4194304;
  bf16* q0    = (bf16*)(ws + 3 * MB32);
  bf16* k0    = (bf16*)(ws + 4 * MB32);
  bf16* Vt    = (bf16*)(ws + 5 * MB32); // dedicated (merged QKV: xq16 still live)
  bf16* attn16 = xkv16;                 // xkv16 dead after the merged QKV GEMM

  // all 6 cvts in one launch
  cvt_multi6<<<dim3(1024, 6), 256, 0, stream>>>(
      x_q, x_kv, Wq, Wk, Wv, Wo,
      xq16, xkv16, wq16, wk16, wv16, wo16,
      Mc * Ec / 8, Ec * Ec / 8);

  // Q, K, V projections as ONE dispatch (y = job); V writes transposed Vt.
  gemm8<<<dim3(256, 3), 512, 0, stream>>>(
      xq16, xkv16, wq16, wk16, wv16, bq, bk, bv,
      q0, k0, Vt, 1, 1, 2, Mc / 256);

  rope_kernel<<<2048, 256, 0, stream>>>(k0, angles, k_rope, 0); // k only (gated)

  attn_kernel<<<1024, 256, 0, stream>>>(q0, k0, Vt, amask, causal, angles, attn16);

  // output projection (f32 out)
  gemm8<<<dim3(256, 1), 512, 0, stream>>>(
      attn16, attn16, wo16, wo16, wo16, bo, bo, bo,
      out, out, out, 0, 0, 0, Mc / 256);
}